// Round 12
// baseline (294.983 us; speedup 1.0000x reference)
//
#include <hip/hip_runtime.h>

#define HH 1024
#define WW 1024
#define NB 16
#define NTH 3
#define BAND 64
#define NBAND (HH/BAND)       // 16
#define NSTRIP 11             // strips of 128 cols, 96-col yield: 11*96 = 1056 >= 1024
#define ACC_BYTES 4096
#define NEGBIG -1e30f

typedef unsigned int u32;
typedef _Float16 hv __attribute__((ext_vector_type(2)));

__device__ __forceinline__ hv pkh(float a, float b){
  auto t = __builtin_amdgcn_cvt_pkrtz(a, b);   // v_cvt_pkrtz_f16_f32
  hv r; __builtin_memcpy(&r, &t, 4); return r;
}
__device__ __forceinline__ hv bph(int idx4, hv v){
  int s; __builtin_memcpy(&s, &v, 4);
  const int r = __builtin_amdgcn_ds_bpermute(idx4, s);
  hv o; __builtin_memcpy(&o, &r, 4); return o;
}
__device__ __forceinline__ hv swph(hv v){      // swap halves
  u32 u; __builtin_memcpy(&u, &v, 4);
  u = (u >> 16) | (u << 16);
  hv o; __builtin_memcpy(&o, &u, 4); return o;
}
// raw stats: sd += 2*(h.f - h.o)^2 ; sr += h.f^2 + h.o^2   (normalize in fss_final)
__device__ __forceinline__ void dstat(hv h, float& sd, float& sr){
  const hv d = h - swph(h);
  sd = __builtin_amdgcn_fdot2(d, d, sd, false);
  sr = __builtin_amdgcn_fdot2(h, h, sr, false);
}

#if __has_builtin(__builtin_amdgcn_rcpf)
#define RCP(x) __builtin_amdgcn_rcpf(x)
#else
#define RCP(x) (1.0f/(x))
#endif
#if __has_builtin(__builtin_amdgcn_exp2f)
#define EXP2(x) __builtin_amdgcn_exp2f(x)
#else
#define EXP2(x) exp2f(x)
#endif

__global__ __launch_bounds__(192) void fss_fused(
    const float* __restrict__ F_, const float* __restrict__ O_,
    double* __restrict__ accum)
{
  const int tid = threadIdx.x;
  const int ln  = tid & 63;
  const int t   = tid >> 6;                    // threshold index (wave id in block)
  const int b   = blockIdx.x;                  // tile id
  const int s   = b % NSTRIP;
  const int rem = b / NSTRIP;
  const int band = rem & (NBAND-1);
  const int img  = rem / NBAND;
  const int y0 = band * BAND;
  const int x0 = 96*s - 16 + 2*ln;             // owned col pair (x0, x0+1)
  const bool colok = ((unsigned)x0 < WW);
  const bool act   = (ln >= 8) && (ln < 56) && colok;

  const float th = 0.5f*(float)t;
  const float EC = 14.426950408889634f*th;     // sig = rcp(1+exp2(-14.43*v + EC))

  const float* F = F_ + (size_t)img*HH*WW;
  const float* O = O_ + (size_t)img*HH*WW;

  // single-threshold vertical window state (f32)
  float c9f0=0, c9f1=0, c9o0=0, c9o1=0, c33f0=0, c33f1=0, c33o0=0, c33o1=0;
  float s1d=0, s1r=0, s9d=0, s9r=0, s33d=0, s33r=0;

  // precomputed ds_bpermute byte indices
  const int i_m1=((ln-1)&63)<<2, i_m2=((ln-2)&63)<<2, i_m4=((ln-4)&63)<<2, i_m8=((ln-8)&63)<<2;
  const int i_p1=((ln+1)&63)<<2, i_p2=((ln+2)&63)<<2, i_p7=((ln+7)&63)<<2, i_p8=((ln+8)&63)<<2;

  #define SIG(v) RCP(1.0f + EXP2(__builtin_fmaf(-14.426950408889634f, (v), EC)))
  #define OBS(v) (((v) > th) ? 1.f : 0.f)

  // ---- warmup: rows [y0-16, y0+16] ----
  #pragma unroll 1
  for (int r = y0-16; r <= y0+16; ++r){
    if ((unsigned)r >= HH) continue;
    float2 fv = {NEGBIG,NEGBIG}, ov = {NEGBIG,NEGBIG};
    if (colok){
      fv = *(const float2*)&F[(size_t)r*WW + x0];
      ov = *(const float2*)&O[(size_t)r*WW + x0];
    }
    const float sf0 = SIG(fv.x), sf1 = SIG(fv.y);
    const float so0 = OBS(ov.x), so1 = OBS(ov.y);
    c33f0 += sf0; c33f1 += sf1; c33o0 += so0; c33o1 += so1;
    if (r >= y0-4 && r <= y0+4){ c9f0 += sf0; c9f1 += sf1; c9o0 += so0; c9o1 += so1; }
    if (r >= y0 && r <= y0+4){
      const float d0 = sf0-so0, d1 = sf1-so1;
      s1d += d0*d0 + d1*d1;
      s1r += sf0*sf0 + so0 + sf1*sf1 + so1;    // so^2 == so
    }
  }

  // ---- main loop: no barriers, no LDS; in-place slide; dot2 raw stats ----
  #pragma unroll 1
  for (int y = y0; y < y0 + BAND; ++y){
    const int ri9 = y+5, ro9 = y-4, ri33 = y+17, ro33 = y-16;
    const bool bi9 = (ri9 < HH), bo9 = (ro9 >= 0), bi33 = (ri33 < HH), bo33 = (ro33 >= 0);
    float2 vi9f={NEGBIG,NEGBIG}, vi9o={NEGBIG,NEGBIG};
    float2 vo9f={NEGBIG,NEGBIG}, vo9o={NEGBIG,NEGBIG};
    float2 vi33f={NEGBIG,NEGBIG}, vi33o={NEGBIG,NEGBIG};
    float2 vo33f={NEGBIG,NEGBIG}, vo33o={NEGBIG,NEGBIG};
    if (colok){
      if (bi9 ){ vi9f  = *(const float2*)&F[(size_t)ri9 *WW + x0]; vi9o  = *(const float2*)&O[(size_t)ri9 *WW + x0]; }
      if (bo9 ){ vo9f  = *(const float2*)&F[(size_t)ro9 *WW + x0]; vo9o  = *(const float2*)&O[(size_t)ro9 *WW + x0]; }
      if (bi33){ vi33f = *(const float2*)&F[(size_t)ri33*WW + x0]; vi33o = *(const float2*)&O[(size_t)ri33*WW + x0]; }
      if (bo33){ vo33f = *(const float2*)&F[(size_t)ro33*WW + x0]; vo33o = *(const float2*)&O[(size_t)ro33*WW + x0]; }
    }

    // horizontal windows + raw stats for row y (state centered at y)
    {
      // 33-window: packed unmasked window tree over column-pair sums
      hv wv = pkh(c33f0 + c33f1, c33o0 + c33o1);
      wv = wv + bph(i_m1, wv);
      wv = wv + bph(i_m2, wv);
      wv = wv + bph(i_m4, wv);
      wv = wv + bph(i_m8, wv);
      const hv c0 = pkh(c33f0, c33o0);
      const hv c1 = pkh(c33f1, c33o1);
      const hv h33_0 = bph(i_p7, wv) + bph(i_p8, c0);
      const hv h33_1 = bph(i_p8, wv) + bph(i_m8, c1);

      // 9-window: packed direct lane taps
      const hv q  = pkh(c9f0 + c9f1, c9o0 + c9o1);
      const hv q0 = pkh(c9f0, c9o0);
      const hv q1 = pkh(c9f1, c9o1);
      const hv mid = q + bph(i_m1, q) + bph(i_p1, q);
      const hv h9_0 = mid + bph(i_m2, q) + bph(i_p2, q0);
      const hv h9_1 = mid + bph(i_p2, q) + bph(i_m2, q1);

      dstat(h9_0,  s9d,  s9r);
      dstat(h9_1,  s9d,  s9r);
      dstat(h33_0, s33d, s33r);
      dstat(h33_1, s33d, s33r);
    }

    // slide vertical windows to center y+1 (+ k=1 stats on entering 9-row)
    if (bi9){
      const float sf0 = SIG(vi9f.x), sf1 = SIG(vi9f.y);
      const float so0 = OBS(vi9o.x), so1 = OBS(vi9o.y);
      c9f0 += sf0; c9f1 += sf1; c9o0 += so0; c9o1 += so1;
      if (ri9 < y0 + BAND){
        const float d0 = sf0-so0, d1 = sf1-so1;
        s1d += d0*d0 + d1*d1;
        s1r += sf0*sf0 + so0 + sf1*sf1 + so1;
      }
    }
    if (bo9){
      const float sf0 = SIG(vo9f.x), sf1 = SIG(vo9f.y);
      const float so0 = OBS(vo9o.x), so1 = OBS(vo9o.y);
      c9f0 -= sf0; c9f1 -= sf1; c9o0 -= so0; c9o1 -= so1;
    }
    if (bi33){
      const float sf0 = SIG(vi33f.x), sf1 = SIG(vi33f.y);
      const float so0 = OBS(vi33o.x), so1 = OBS(vi33o.y);
      c33f0 += sf0; c33f1 += sf1; c33o0 += so0; c33o1 += so1;
    }
    if (bo33){
      const float sf0 = SIG(vo33f.x), sf1 = SIG(vo33f.y);
      const float so0 = OBS(vo33o.x), so1 = OBS(vo33o.y);
      c33f0 -= sf0; c33f1 -= sf1; c33o0 -= so0; c33o1 -= so1;
    }
  }

  // ---- mask halo lanes, wave-reduce, per-wave f64 atomics ----
  if (!act){ s1d=0; s1r=0; s9d=0; s9r=0; s33d=0; s33r=0; }
  #define WRED(v) { _Pragma("unroll") \
    for (int d = 32; d; d >>= 1) v += __shfl_down(v, (unsigned)d, 64); }
  WRED(s1d);  WRED(s1r);
  WRED(s9d);  WRED(s9r);
  WRED(s33d); WRED(s33r);
  if (ln == 0){
    double* a = accum + (size_t)(img*NTH + t)*6;
    atomicAdd(&a[0], (double)s1d);
    atomicAdd(&a[1], (double)s1r);
    atomicAdd(&a[2], (double)s9d);
    atomicAdd(&a[3], (double)s9r);
    atomicAdd(&a[4], (double)s33d);
    atomicAdd(&a[5], (double)s33r);
  }
}

__global__ void fss_final(const double* __restrict__ accum, float* __restrict__ out)
{
  if (threadIdx.x == 0 && blockIdx.x == 0){
    const double HW = (double)HH * (double)WW;
    // raw k=9/33 stats: sd holds 2*(hf-ho)^2 sums, sr holds hf^2+ho^2 sums
    const double msc[3] = {1.0, 2.0*6561.0, 2.0*1185921.0};
    const double rsc[3] = {1.0, 6561.0, 1185921.0};
    double total = 0.0;
    for (int t = 0; t < NTH; ++t){
      for (int k = 0; k < 3; ++k){
        double sum = 0.0;
        for (int img = 0; img < NB; ++img){
          const double* a = accum + (size_t)(img*NTH + t)*6 + (size_t)k*2;
          const double mse  = a[0] / (msc[k]*HW);
          const double mref = a[1] / (rsc[k]*HW);
          sum += 1.0 - mse / (mref + 1e-8);
        }
        total += sum / (double)NB;
      }
    }
    out[0] = (float)(1.0 - total/9.0);
  }
}

extern "C" void kernel_launch(void* const* d_in, const int* in_sizes, int n_in,
                              void* d_out, int out_size, void* d_ws, size_t ws_size,
                              hipStream_t stream)
{
  const float* fcst = (const float*)d_in[0];
  const float* obs  = (const float*)d_in[1];
  float* out = (float*)d_out;
  double* accum = (double*)d_ws;

  const int nblocks = NSTRIP * NBAND * NB;   // 2816 blocks x 3 waves = 8448 waves

  hipMemsetAsync(d_ws, 0, ACC_BYTES, stream);
  hipLaunchKernelGGL(fss_fused, dim3(nblocks), dim3(192), 0, stream,
                     fcst, obs, accum);
  hipLaunchKernelGGL(fss_final, dim3(1), dim3(64), 0, stream, accum, out);
}

// Round 13
// 265.137 us; speedup vs baseline: 1.1126x; 1.1126x over previous
//
#include <hip/hip_runtime.h>

#define HH 1024
#define WW 1024
#define NB 16
#define NTH 3
#define BAND 64
#define NBAND (HH/BAND)       // 16
#define NSTRIP 11             // strips of 128 cols, 96-col yield: 11*96 = 1056 >= 1024
#define ACC_BYTES 4096
#define NEGBIG -1e30f

typedef unsigned int u32;
typedef _Float16 hv __attribute__((ext_vector_type(2)));

__device__ __forceinline__ hv pkh(float a, float b){
  auto t = __builtin_amdgcn_cvt_pkrtz(a, b);   // v_cvt_pkrtz_f16_f32
  hv r; __builtin_memcpy(&r, &t, 4); return r;
}
__device__ __forceinline__ hv bph(int idx4, hv v){
  int s; __builtin_memcpy(&s, &v, 4);
  const int r = __builtin_amdgcn_ds_bpermute(idx4, s);
  hv o; __builtin_memcpy(&o, &r, 4); return o;
}
__device__ __forceinline__ hv swph(hv v){      // swap halves
  u32 u; __builtin_memcpy(&u, &v, 4);
  u = (u >> 16) | (u << 16);
  hv o; __builtin_memcpy(&o, &u, 4); return o;
}
// raw stats: sd += 2*(h.f - h.o)^2 ; sr += h.f^2 + h.o^2   (normalize in fss_final)
__device__ __forceinline__ void dstat(hv h, float& sd, float& sr){
  const hv d = h - swph(h);
  sd = __builtin_amdgcn_fdot2(d, d, sd, false);
  sr = __builtin_amdgcn_fdot2(h, h, sr, false);
}

#if __has_builtin(__builtin_amdgcn_rcpf)
#define RCP(x) __builtin_amdgcn_rcpf(x)
#else
#define RCP(x) (1.0f/(x))
#endif
#if __has_builtin(__builtin_amdgcn_exp2f)
#define EXP2(x) __builtin_amdgcn_exp2f(x)
#else
#define EXP2(x) exp2f(x)
#endif

__global__ __launch_bounds__(192) void fss_fused(
    const float* __restrict__ F_, const float* __restrict__ O_,
    double* __restrict__ accum)
{
  const int tid = threadIdx.x;
  const int ln  = tid & 63;
  const int t   = tid >> 6;                    // threshold index (wave id in block)
  const int b   = blockIdx.x;                  // tile id
  const int s   = b % NSTRIP;
  const int rem = b / NSTRIP;
  const int band = rem & (NBAND-1);
  const int img  = rem / NBAND;
  const int y0 = band * BAND;
  const int xbase = 96*s - 16;                 // strip col base (incl. halo)
  const int x0 = xbase + 2*ln;                 // owned col pair (x0, x0+1)
  const bool colok = ((unsigned)x0 < WW);
  const bool act   = (ln >= 8) && (ln < 56) && colok;

  const float th = 0.5f*(float)t;
  const float EC = 14.426950408889634f*th;     // sig = rcp(1+exp2(-14.43*v + EC))

  const float* F = F_ + (size_t)img*HH*WW;
  const float* O = O_ + (size_t)img*HH*WW;

  // slot layout: 0:i9F 1:i9O 2:o9F 3:o9O 4:i33F 5:i33O 6:o33F 7:o33O
  __shared__ float lds[2][8][128];

  // single-threshold vertical window state (f32)
  float c9f0=0, c9f1=0, c9o0=0, c9o1=0, c33f0=0, c33f1=0, c33o0=0, c33o1=0;
  float s1d=0, s1r=0, s9d=0, s9r=0, s33d=0, s33r=0;

  // precomputed ds_bpermute byte indices
  const int i_m1=((ln-1)&63)<<2, i_m2=((ln-2)&63)<<2, i_m4=((ln-4)&63)<<2, i_m8=((ln-8)&63)<<2;
  const int i_p1=((ln+1)&63)<<2, i_p2=((ln+2)&63)<<2, i_p7=((ln+7)&63)<<2, i_p8=((ln+8)&63)<<2;

  #define SIG(v) RCP(1.0f + EXP2(__builtin_fmaf(-14.426950408889634f, (v), EC)))
  #define OBS(v) (((v) > th) ? 1.f : 0.f)

  // ---- warmup: rows [y0-16, y0+16] (direct loads; 33 rows, L1-shared) ----
  #pragma unroll 1
  for (int r = y0-16; r <= y0+16; ++r){
    if ((unsigned)r >= HH) continue;
    float2 fv = {NEGBIG,NEGBIG}, ov = {NEGBIG,NEGBIG};
    if (colok){
      fv = *(const float2*)&F[(size_t)r*WW + x0];
      ov = *(const float2*)&O[(size_t)r*WW + x0];
    }
    const float sf0 = SIG(fv.x), sf1 = SIG(fv.y);
    const float so0 = OBS(ov.x), so1 = OBS(ov.y);
    c33f0 += sf0; c33f1 += sf1; c33o0 += so0; c33o1 += so1;
    if (r >= y0-4 && r <= y0+4){ c9f0 += sf0; c9f1 += sf1; c9o0 += so0; c9o1 += so1; }
    if (r >= y0 && r <= y0+4){
      const float d0 = sf0-so0, d1 = sf1-so1;
      s1d += d0*d0 + d1*d1;
      s1r += sf0*sf0 + so0 + sf1*sf1 + so1;    // so^2 == so
    }
  }

  // per-iteration staging: compute guarded global load + LDS target
  #define STAGE1(i, v, pdst) {                                             \
    const int slot_ = (i) >> 6, c2_ = (i) & 63;                            \
    const int q_ = slot_ >> 1;                                             \
    const int off_ = (q_==0) ? 5 : ((q_==1) ? -4 : ((q_==2) ? 17 : -16));  \
    const int row_ = y + off_;                                             \
    const int gcol_ = xbase + 2*c2_;                                       \
    v = make_float2(NEGBIG, NEGBIG);                                       \
    if ((unsigned)row_ < HH && (unsigned)gcol_ < WW){                      \
      const float* bp_ = (slot_ & 1) ? O : F;                              \
      v = *(const float2*)&bp_[(size_t)row_*WW + gcol_];                   \
    }                                                                      \
    pdst = (float2*)&lds[p][slot_][2*c2_];                                 \
  }

  // ---- main loop: 1 barrier/row, LDS-staged boundary rows shared by 3 waves ----
  #pragma unroll 1
  for (int y = y0; y < y0 + BAND; ++y){
    const int p = y & 1;

    // issue stage loads early (512 float2 staged by 192 threads: 3 strided slices)
    float2 va, vb, vc; float2 *pa, *pb, *pc;
    STAGE1(tid, va, pa);
    STAGE1(tid+192, vb, pb);
    const bool hasC = (tid < 512-384);
    if (hasC) STAGE1(tid+384, vc, pc);

    // horizontal windows + raw stats for row y (state centered at y; no LDS dep)
    {
      // 33-window: packed unmasked window tree over column-pair sums
      hv wv = pkh(c33f0 + c33f1, c33o0 + c33o1);
      wv = wv + bph(i_m1, wv);
      wv = wv + bph(i_m2, wv);
      wv = wv + bph(i_m4, wv);
      wv = wv + bph(i_m8, wv);
      const hv c0 = pkh(c33f0, c33o0);
      const hv c1 = pkh(c33f1, c33o1);
      const hv h33_0 = bph(i_p7, wv) + bph(i_p8, c0);
      const hv h33_1 = bph(i_p8, wv) + bph(i_m8, c1);

      // 9-window: packed direct lane taps
      const hv q  = pkh(c9f0 + c9f1, c9o0 + c9o1);
      const hv q0 = pkh(c9f0, c9o0);
      const hv q1 = pkh(c9f1, c9o1);
      const hv mid = q + bph(i_m1, q) + bph(i_p1, q);
      const hv h9_0 = mid + bph(i_m2, q) + bph(i_p2, q0);
      const hv h9_1 = mid + bph(i_p2, q) + bph(i_m2, q1);

      dstat(h9_0,  s9d,  s9r);
      dstat(h9_1,  s9d,  s9r);
      dstat(h33_0, s33d, s33r);
      dstat(h33_1, s33d, s33r);
    }

    // write staged rows, publish to all 3 waves
    *pa = va; *pb = vb;
    if (hasC) *pc = vc;
    __syncthreads();

    // slide vertical windows to center y+1 from LDS (sentinels absorb all guards)
    {
      const float2 vi9f  = *(const float2*)&lds[p][0][2*ln];
      const float2 vi9o  = *(const float2*)&lds[p][1][2*ln];
      const float2 vo9f  = *(const float2*)&lds[p][2][2*ln];
      const float2 vo9o  = *(const float2*)&lds[p][3][2*ln];
      const float2 vi33f = *(const float2*)&lds[p][4][2*ln];
      const float2 vi33o = *(const float2*)&lds[p][5][2*ln];
      const float2 vo33f = *(const float2*)&lds[p][6][2*ln];
      const float2 vo33o = *(const float2*)&lds[p][7][2*ln];

      {
        const float sf0 = SIG(vi9f.x), sf1 = SIG(vi9f.y);
        const float so0 = OBS(vi9o.x), so1 = OBS(vi9o.y);
        c9f0 += sf0; c9f1 += sf1; c9o0 += so0; c9o1 += so1;
        if (y+5 < y0 + BAND){
          const float d0 = sf0-so0, d1 = sf1-so1;
          s1d += d0*d0 + d1*d1;
          s1r += sf0*sf0 + so0 + sf1*sf1 + so1;
        }
      }
      {
        const float sf0 = SIG(vo9f.x), sf1 = SIG(vo9f.y);
        const float so0 = OBS(vo9o.x), so1 = OBS(vo9o.y);
        c9f0 -= sf0; c9f1 -= sf1; c9o0 -= so0; c9o1 -= so1;
      }
      {
        const float sf0 = SIG(vi33f.x), sf1 = SIG(vi33f.y);
        const float so0 = OBS(vi33o.x), so1 = OBS(vi33o.y);
        c33f0 += sf0; c33f1 += sf1; c33o0 += so0; c33o1 += so1;
      }
      {
        const float sf0 = SIG(vo33f.x), sf1 = SIG(vo33f.y);
        const float so0 = OBS(vo33o.x), so1 = OBS(vo33o.y);
        c33f0 -= sf0; c33f1 -= sf1; c33o0 -= so0; c33o1 -= so1;
      }
    }
  }

  // ---- mask halo lanes, wave-reduce, per-wave f64 atomics ----
  if (!act){ s1d=0; s1r=0; s9d=0; s9r=0; s33d=0; s33r=0; }
  #define WRED(v) { _Pragma("unroll") \
    for (int d = 32; d; d >>= 1) v += __shfl_down(v, (unsigned)d, 64); }
  WRED(s1d);  WRED(s1r);
  WRED(s9d);  WRED(s9r);
  WRED(s33d); WRED(s33r);
  if (ln == 0){
    double* a = accum + (size_t)(img*NTH + t)*6;
    atomicAdd(&a[0], (double)s1d);
    atomicAdd(&a[1], (double)s1r);
    atomicAdd(&a[2], (double)s9d);
    atomicAdd(&a[3], (double)s9r);
    atomicAdd(&a[4], (double)s33d);
    atomicAdd(&a[5], (double)s33r);
  }
}

__global__ void fss_final(const double* __restrict__ accum, float* __restrict__ out)
{
  if (threadIdx.x == 0 && blockIdx.x == 0){
    const double HW = (double)HH * (double)WW;
    // raw k=9/33 stats: sd holds 2*(hf-ho)^2 sums, sr holds hf^2+ho^2 sums
    const double msc[3] = {1.0, 2.0*6561.0, 2.0*1185921.0};
    const double rsc[3] = {1.0, 6561.0, 1185921.0};
    double total = 0.0;
    for (int t = 0; t < NTH; ++t){
      for (int k = 0; k < 3; ++k){
        double sum = 0.0;
        for (int img = 0; img < NB; ++img){
          const double* a = accum + (size_t)(img*NTH + t)*6 + (size_t)k*2;
          const double mse  = a[0] / (msc[k]*HW);
          const double mref = a[1] / (rsc[k]*HW);
          sum += 1.0 - mse / (mref + 1e-8);
        }
        total += sum / (double)NB;
      }
    }
    out[0] = (float)(1.0 - total/9.0);
  }
}

extern "C" void kernel_launch(void* const* d_in, const int* in_sizes, int n_in,
                              void* d_out, int out_size, void* d_ws, size_t ws_size,
                              hipStream_t stream)
{
  const float* fcst = (const float*)d_in[0];
  const float* obs  = (const float*)d_in[1];
  float* out = (float*)d_out;
  double* accum = (double*)d_ws;

  const int nblocks = NSTRIP * NBAND * NB;   // 2816 blocks x 3 waves = 8448 waves

  hipMemsetAsync(d_ws, 0, ACC_BYTES, stream);
  hipLaunchKernelGGL(fss_fused, dim3(nblocks), dim3(192), 0, stream,
                     fcst, obs, accum);
  hipLaunchKernelGGL(fss_final, dim3(1), dim3(64), 0, stream, accum, out);
}